// Round 3
// baseline (3513.980 us; speedup 1.0000x reference)
//
#include <hip/hip_runtime.h>
#include <math.h>

#define NB    4096   // batch N
#define FEAT  1024
#define MSUP  512    // SUPPORT
#define G4    4096   // 4*FEAT
#define NWAYS 20     // n_ways fixed to 20 per setup_inputs()

typedef _Float16 f16;
typedef f16 f16x8 __attribute__((ext_vector_type(8)));
typedef f16 f16x4 __attribute__((ext_vector_type(4)));
typedef float f32x16 __attribute__((ext_vector_type(16)));
typedef unsigned int u32;
#define GLOBAL_AS __attribute__((address_space(1)))
#define LDS_AS    __attribute__((address_space(3)))

__device__ __forceinline__ void load_lds16(const void* g, void* l) {
    __builtin_amdgcn_global_load_lds((const GLOBAL_AS u32*)g, (LDS_AS u32*)l, 16, 0, 0);
}

// ---------------- f16 MFMA NT GEMM, 32x32x16 frags, swizzled LDS ----------------
// C[m,n] = sum_k A[m,k]*B[n,k]; optional f16 initC (same ldc) + two f32 col biases.
// LDS chunk swizzle: 16B chunk c of row r stored at physical chunk c^(r&3); the
// global_load_lds source address is swizzled to match (wave-uniform dest + lane*16).
template<int BM, int BN, int WROWS, int WCOLS, bool OUTF16, bool HASINIT, bool HASBIAS>
__global__ __launch_bounds__(256) void mfma_nt(
    void* __restrict__ Cv, int ldc,
    const f16* __restrict__ A, int lda,
    const f16* __restrict__ B, int ldb, int K,
    const f16* __restrict__ initC,
    const float* __restrict__ bias1, const float* __restrict__ bias2)
{
    constexpr int BK = 32;
    constexpr int WM = BM / WROWS, WN = BN / WCOLS;
    constexpr int FM = WM / 32,   FN = WN / 32;
    __shared__ f16 As[BM][BK];
    __shared__ f16 Bs[BN][BK];
    const int tid  = threadIdx.x;
    const int lane = tid & 63;
    const int wrow = (tid >> 6) % WROWS, wcol = (tid >> 6) / WROWS;
    const int bm = blockIdx.y * BM, bn = blockIdx.x * BN;
    const int lc = lane & 31;   // row/col within 32-frag
    const int lh = lane >> 5;   // k-subgroup

    f32x16 acc[FM][FN] = {};

    #pragma unroll 1
    for (int k0 = 0; k0 < K; k0 += BK) {
        __syncthreads();
        #pragma unroll
        for (int t = 0; t < (BM * 4) / 256; ++t) {
            int s = t * 256 + tid;
            int row = s >> 2;
            int c = (s & 3) ^ (row & 3);
            load_lds16(A + (size_t)(bm + row) * lda + k0 + c * 8,
                       &As[0][0] + ((size_t)t * 256 + (tid & ~63)) * 8);
        }
        #pragma unroll
        for (int t = 0; t < (BN * 4) / 256; ++t) {
            int s = t * 256 + tid;
            int row = s >> 2;
            int c = (s & 3) ^ (row & 3);
            load_lds16(B + (size_t)(bn + row) * ldb + k0 + c * 8,
                       &Bs[0][0] + ((size_t)t * 256 + (tid & ~63)) * 8);
        }
        __syncthreads();
        // frag reads: A[m=lane&31][k = h*16 + (lane>>5)*8 + j]
        f16x8 af[FM][2], bf[FN][2];
        #pragma unroll
        for (int i = 0; i < FM; ++i) {
            int row = wrow * WM + i * 32 + lc;
            #pragma unroll
            for (int h = 0; h < 2; ++h) {
                int c = (h * 2 + lh) ^ (row & 3);
                af[i][h] = *(const f16x8*)&As[row][c * 8];
            }
        }
        #pragma unroll
        for (int j = 0; j < FN; ++j) {
            int row = wcol * WN + j * 32 + lc;
            #pragma unroll
            for (int h = 0; h < 2; ++h) {
                int c = (h * 2 + lh) ^ (row & 3);
                bf[j][h] = *(const f16x8*)&Bs[row][c * 8];
            }
        }
        #pragma unroll
        for (int h = 0; h < 2; ++h)
            #pragma unroll
            for (int i = 0; i < FM; ++i)
                #pragma unroll
                for (int j = 0; j < FN; ++j)
                    acc[i][j] = __builtin_amdgcn_mfma_f32_32x32x16_f16(af[i][h], bf[j][h], acc[i][j], 0, 0, 0);
    }

    // epilogue: C/D layout col=lane&31, row=(reg&3)+8*(reg>>2)+4*(lane>>5)
    #pragma unroll
    for (int i = 0; i < FM; ++i) {
        #pragma unroll
        for (int j = 0; j < FN; ++j) {
            const int col   = bn + wcol * WN + j * 32 + lc;
            const int rbase = bm + wrow * WM + i * 32 + 4 * lh;
            float badd = 0.f;
            if (HASBIAS) badd = bias1[col] + bias2[col];
            #pragma unroll
            for (int reg = 0; reg < 16; ++reg) {
                int row = rbase + (reg & 3) + 8 * (reg >> 2);
                size_t off = (size_t)row * ldc + col;
                float v = acc[i][j][reg] + badd;
                if (HASINIT) v += (float)initC[off];
                if (OUTF16) ((f16*)Cv)[off] = (f16)v;
                else        ((float*)Cv)[off] = v;
            }
        }
    }
}

// -------- softmax along contiguous rows; in f32 [rows][4096] -> out f16 --------
__global__ __launch_bounds__(256) void softmax_rows_kernel(
    const float* __restrict__ X, f16* __restrict__ Y)
{
    const int row = blockIdx.x;
    const float* x = X + (size_t)row * NB;
    f16* y = Y + (size_t)row * NB;
    const int tid = threadIdx.x;
    float v[16];
    float mx = -1e30f;
    #pragma unroll
    for (int i = 0; i < 16; ++i) { v[i] = x[tid + (i << 8)]; mx = fmaxf(mx, v[i]); }
    #pragma unroll
    for (int off = 32; off > 0; off >>= 1) mx = fmaxf(mx, __shfl_down(mx, off));
    __shared__ float sm[4];
    if ((tid & 63) == 0) sm[tid >> 6] = mx;
    __syncthreads();
    mx = fmaxf(fmaxf(sm[0], sm[1]), fmaxf(sm[2], sm[3]));
    float s = 0.f;
    #pragma unroll
    for (int i = 0; i < 16; ++i) { v[i] = __expf(v[i] - mx); s += v[i]; }
    #pragma unroll
    for (int off = 32; off > 0; off >>= 1) s += __shfl_down(s, off);
    __shared__ float ss[4];
    if ((tid & 63) == 0) ss[tid >> 6] = s;
    __syncthreads();
    s = ss[0] + ss[1] + ss[2] + ss[3];
    const float inv = 1.f / s;
    #pragma unroll
    for (int i = 0; i < 16; ++i) y[tid + (i << 8)] = (f16)(v[i] * inv);
}

// -------- transpose: in [R][C] (Tin) -> out f16 [C][R] --------
template<typename Tin>
__global__ __launch_bounds__(256) void transpose_f16_kernel(
    const Tin* __restrict__ in, f16* __restrict__ out, int R, int C)
{
    __shared__ f16 t[64][65];
    const int r0 = blockIdx.y * 64, c0 = blockIdx.x * 64;
    const int lr = threadIdx.x & 63, lw = threadIdx.x >> 6;
    #pragma unroll
    for (int i = 0; i < 16; ++i) {
        int rr = lw * 16 + i;
        t[rr][lr] = (f16)in[(size_t)(r0 + rr) * C + c0 + lr];
    }
    __syncthreads();
    #pragma unroll
    for (int i = 0; i < 16; ++i) {
        int cc = lw * 16 + i;
        out[(size_t)(c0 + cc) * R + r0 + lr] = t[lr][cc];
    }
}

// -------- conversions --------
__global__ __launch_bounds__(256) void cvt_f16_kernel(
    const float* __restrict__ in, f16* __restrict__ out, int n)
{
    int idx = (blockIdx.x * 256 + threadIdx.x) * 4;
    if (idx < n) {
        float4 v = *(const float4*)(in + idx);
        f16x4 o = {(f16)v.x, (f16)v.y, (f16)v.z, (f16)v.w};
        *(f16x4*)(out + idx) = o;
    }
}

// f [NB][1024] f32 -> xh[:,1024:2048] f16 (row stride 2048)
__global__ __launch_bounds__(256) void cvt_f_to_xh(
    const float* __restrict__ f, f16* __restrict__ xh)
{
    int idx = (blockIdx.x * 256 + threadIdx.x) * 4;
    int n = idx >> 10, k = idx & 1023;
    float4 v = *(const float4*)(f + idx);
    f16x4 o = {(f16)v.x, (f16)v.y, (f16)v.z, (f16)v.w};
    *(f16x4*)(xh + (size_t)n * 2048 + 1024 + k) = o;
}

// W_f[j][k] = Wih[j][k], k<1024  (f16)
__global__ __launch_bounds__(256) void cvt_wf(
    const float* __restrict__ Wih, f16* __restrict__ Wf)
{
    int idx = (blockIdx.x * 256 + threadIdx.x) * 4;
    int j = idx >> 10, k = idx & 1023;
    float4 v = *(const float4*)(Wih + (size_t)j * 2048 + k);
    f16x4 o = {(f16)v.x, (f16)v.y, (f16)v.z, (f16)v.w};
    *(f16x4*)(Wf + idx) = o;
}

// W_cat[j][0:1024] = Wih[j][1024:2048]; W_cat[j][1024:2048] = Whh[j][:]
__global__ __launch_bounds__(256) void cvt_wcat(
    const float* __restrict__ Wih, const float* __restrict__ Whh, f16* __restrict__ Wc)
{
    int idx = (blockIdx.x * 256 + threadIdx.x) * 4;
    int j = idx >> 11, k = idx & 2047;
    const float* src = (k < 1024) ? (Wih + (size_t)j * 2048 + 1024 + k)
                                  : (Whh + (size_t)j * 1024 + (k - 1024));
    float4 v = *(const float4*)src;
    f16x4 o = {(f16)v.x, (f16)v.y, (f16)v.z, (f16)v.w};
    *(f16x4*)(Wc + idx) = o;
}

// -------- LSTM cell; gates f16 [NB][4F] (i,f,g,o); h = o*tanh(c)+f --------
// Writes f32 h to d_out and f16 h into xh[:,1024:2048].
__global__ __launch_bounds__(256) void lstm_cell_kernel(
    const f16* __restrict__ gates, const float* __restrict__ f,
    float* __restrict__ c, float* __restrict__ h, f16* __restrict__ xh, int first)
{
    const int idx = blockIdx.x * 256 + threadIdx.x;
    const int n = idx >> 10, k = idx & 1023;
    const f16* g = gates + (size_t)n * G4;
    float ig = (float)g[k], fg = (float)g[k + 1024];
    float gg = (float)g[k + 2048], og = (float)g[k + 3072];
    float i_ = 1.f / (1.f + __expf(-ig));
    float f_ = 1.f / (1.f + __expf(-fg));
    float g_ = tanhf(gg);
    float o_ = 1.f / (1.f + __expf(-og));
    float cn = i_ * g_ + (first ? 0.f : f_ * c[idx]);
    c[idx] = cn;
    float hn = o_ * tanhf(cn) + f[idx];
    h[idx] = hn;
    xh[(size_t)n * 2048 + 1024 + k] = (f16)hn;
}

extern "C" void kernel_launch(void* const* d_in, const int* in_sizes, int n_in,
                              void* d_out, int out_size, void* d_ws, size_t ws_size,
                              hipStream_t stream) {
    const float* f   = (const float*)d_in[0];   // [NB, FEAT]
    const float* G   = (const float*)d_in[1];   // [MSUP, FEAT]
    const float* Wih = (const float*)d_in[2];   // [G4, 2*FEAT]
    const float* Whh = (const float*)d_in[3];   // [G4, FEAT]
    const float* bih = (const float*)d_in[4];   // [G4]
    const float* bhh = (const float*)d_in[5];   // [G4]
    float* h = (float*)d_out;                   // [NB, FEAT]

    char* W = (char*)d_ws;
    f16*   xh      = (f16*)(W);                          // 16 MB [NB][2048]: cols 0:1024=r, 1024:2048=h (init f)
    f16*   pre_h   = (f16*)(W + (size_t)(16 << 20));     // 32 MB [NB][G4]
    f16*   gates_h = (f16*)(W + (size_t)(48 << 20));     // 32 MB [NB][G4]
    float* aT      = (float*)(W + (size_t)(80 << 20));   //  8 MB [MSUP][NB]
    f16*   aTh     = (f16*)(W + (size_t)(88 << 20));     //  4 MB [MSUP][NB]
    f16*   a_h     = (f16*)(W + (size_t)(92 << 20));     //  4 MB [NB][MSUP]
    float* c       = (float*)(W + (size_t)(96 << 20));   // 16 MB [NB][FEAT]
    f16*   W_f     = (f16*)(W + (size_t)(112 << 20));    //  8 MB [G4][FEAT]
    f16*   W_cat   = (f16*)(W + (size_t)(120 << 20));    // 16 MB [G4][2048]
    f16*   G_h     = (f16*)(W + (size_t)(136 << 20));    //  1 MB [MSUP][FEAT]
    f16*   GT_h    = (f16*)(W + (size_t)(137 << 20));    //  1 MB [FEAT][MSUP]

    const f16* NF = nullptr;
    const dim3 blk(256);

    // one-time conversions (every call — ws is re-poisoned)
    cvt_f_to_xh<<<(NB * FEAT) / 1024, blk, 0, stream>>>(f, xh);
    cvt_wf<<<(G4 * FEAT) / 1024, blk, 0, stream>>>(Wih, W_f);
    cvt_wcat<<<(G4 * 2 * FEAT) / 1024, blk, 0, stream>>>(Wih, Whh, W_cat);
    cvt_f16_kernel<<<(MSUP * FEAT) / 1024, blk, 0, stream>>>(G, G_h, MSUP * FEAT);
    transpose_f16_kernel<float><<<dim3(FEAT / 64, MSUP / 64), blk, 0, stream>>>(G, GT_h, MSUP, FEAT);

    // pre = f @ W_f^T + b_ih + b_hh   (constant across iterations)
    mfma_nt<128, 128, 2, 2, true, false, true><<<dim3(G4 / 128, NB / 128), blk, 0, stream>>>(
        pre_h, G4,
        xh + 1024, 2048, W_f, FEAT, FEAT,
        NF, bih, bhh);

    for (int it = 0; it < NWAYS; ++it) {
        // aT[m][n] = G[m]·h[n]  (h lives at xh[:,1024:2048])
        mfma_nt<64, 128, 2, 2, false, false, false><<<dim3(NB / 128, MSUP / 64), blk, 0, stream>>>(
            aT, NB,
            G_h, FEAT, xh + 1024, 2048, FEAT,
            NF, nullptr, nullptr);

        softmax_rows_kernel<<<MSUP, blk, 0, stream>>>(aT, aTh);

        // a_h[n][m] = aTh[m][n]
        transpose_f16_kernel<f16><<<dim3(NB / 64, MSUP / 64), blk, 0, stream>>>(aTh, a_h, MSUP, NB);

        // r[n][kf] = sum_m a[n][m]*GT[kf][m]  → written into xh[:,0:1024] (ldc=2048)
        mfma_nt<128, 128, 2, 2, true, false, false><<<dim3(FEAT / 128, NB / 128), blk, 0, stream>>>(
            xh, 2048,
            a_h, MSUP, GT_h, MSUP, MSUP,
            NF, nullptr, nullptr);

        // gates = pre + [r|h] @ W_cat^T   (single pass, K=2048)
        mfma_nt<128, 128, 2, 2, true, true, false><<<dim3(G4 / 128, NB / 128), blk, 0, stream>>>(
            gates_h, G4,
            xh, 2048, W_cat, 2048, 2048,
            pre_h, nullptr, nullptr);

        lstm_cell_kernel<<<(NB * FEAT) / 256, blk, 0, stream>>>(gates_h, f, c, h, xh, it == 0);
    }
}